// Round 5
// baseline (498.676 us; speedup 1.0000x reference)
//
#include <hip/hip_runtime.h>

#define NB 16
#define NS 512
#define ND 256
#define NH 8
#define NFB 128
#define NK 64
#define NFC 32

using f16 = _Float16;
using f16x4 = __attribute__((ext_vector_type(4))) f16;
using f16x8 = __attribute__((ext_vector_type(8))) f16;
using f32x4 = __attribute__((ext_vector_type(4))) float;

__device__ inline float waveReduceSum(float v) {
    #pragma unroll
    for (int off = 32; off; off >>= 1) v += __shfl_down(v, off);
    return v;
}

__device__ inline f32x4 mfma16(f16x8 a, f16x8 b, f32x4 c) {
    return __builtin_amdgcn_mfma_f32_16x16x32_f16(a, b, c, 0, 0, 0);
}

// ---------------------------------------------------------------- prep: mt | convert | bsum | cv in one dispatch
__global__ __launch_bounds__(256) void k_prep(const float* __restrict__ W1, const float* __restrict__ W2,
                                              f16* __restrict__ Mth,
                                              const float* __restrict__ Et_in, const float* __restrict__ Ei_in,
                                              f16* __restrict__ Ot, f16* __restrict__ Oi,
                                              const float* __restrict__ Bt_in, const float* __restrict__ Bi_in,
                                              float* __restrict__ Bt, float* __restrict__ Bi,
                                              const float* __restrict__ Ct, const float* __restrict__ Ci,
                                              float* __restrict__ Cv) {
    __shared__ float Wa[64][36];
    __shared__ float Wb[64][36];
    int bid = blockIdx.x;
    int tid = threadIdx.x;

    if (bid < 128) {
        // ---- Mt[h][j][i] = sum_e W2[h,j,e]*W1[h,i,e]
        int h  = bid >> 4;
        int j0 = ((bid >> 2) & 3) * 64;
        int i0 = (bid & 3) * 64;
        const float* A  = W2 + (size_t)h * ND * ND;
        const float* Bm = W1 + (size_t)h * ND * ND;
        int r = tid >> 4, c = tid & 15;
        float acc[4][4] = {};
        for (int d0 = 0; d0 < ND; d0 += 32) {
            __syncthreads();
            #pragma unroll
            for (int i = 0; i < 2; ++i) {
                int sid = tid + i * 256;
                int row = sid >> 3, seg = sid & 7;
                *(float4*)&Wa[row][seg * 4] = *(const float4*)&A [(size_t)(j0 + row) * ND + d0 + seg * 4];
                *(float4*)&Wb[row][seg * 4] = *(const float4*)&Bm[(size_t)(i0 + row) * ND + d0 + seg * 4];
            }
            __syncthreads();
            #pragma unroll 8
            for (int d = 0; d < 32; ++d) {
                float a0 = Wa[r*4+0][d], a1 = Wa[r*4+1][d], a2 = Wa[r*4+2][d], a3 = Wa[r*4+3][d];
                float b0 = Wb[c*4+0][d], b1 = Wb[c*4+1][d], b2 = Wb[c*4+2][d], b3 = Wb[c*4+3][d];
                acc[0][0] += a0*b0; acc[0][1] += a0*b1; acc[0][2] += a0*b2; acc[0][3] += a0*b3;
                acc[1][0] += a1*b0; acc[1][1] += a1*b1; acc[1][2] += a1*b2; acc[1][3] += a1*b3;
                acc[2][0] += a2*b0; acc[2][1] += a2*b1; acc[2][2] += a2*b2; acc[2][3] += a2*b3;
                acc[3][0] += a3*b0; acc[3][1] += a3*b1; acc[3][2] += a3*b2; acc[3][3] += a3*b3;
            }
        }
        #pragma unroll
        for (int a = 0; a < 4; ++a)
            #pragma unroll
            for (int bb = 0; bb < 4; ++bb)
                Mth[(size_t)h * ND * ND + (size_t)(j0 + r * 4 + a) * ND + (i0 + c * 4 + bb)] = (f16)acc[a][bb];
    } else if (bid < 128 + 4096) {
        // ---- convert E -> f16
        const int n4 = NB * NS * ND / 4;
        int i = (bid - 128) * 256 + tid;
        const float* src; f16* dst;
        if (i < n4) { src = Et_in; dst = Ot; }
        else        { src = Ei_in; dst = Oi; i -= n4; }
        float4 v = ((const float4*)src)[i];
        f16x4 o = { (f16)v.x, (f16)v.y, (f16)v.z, (f16)v.w };
        ((f16x4*)dst)[i] = o;
    } else if (bid < 128 + 8192) {
        // ---- Bvec = sum over FB
        int wid = ((bid - 128 - 4096) * 256 + tid) >> 6;
        int lane = tid & 63;
        const float* src; float* dst; int row;
        if (wid < NB * NS) { src = Bt_in; dst = Bt; row = wid; }
        else               { src = Bi_in; dst = Bi; row = wid - NB * NS; }
        float2 v = ((const float2*)(src + (size_t)row * NFB))[lane];
        float s = waveReduceSum(v.x + v.y);
        if (lane == 0) dst[row] = s;
    } else {
        // ---- Cv = 0.5*KLD(Ci,Cm)+0.5*KLD(Ct,Cm)
        int gw = ((bid - 128 - 8192) * 256 + tid) >> 6;
        int lane = tid & 63;
        const float* pt = Ct + ((size_t)gw * NK + lane) * NFC;
        const float* pi = Ci + ((size_t)gw * NK + lane) * NFC;
        float st = 0.f, si = 0.f;
        #pragma unroll
        for (int j = 0; j < NFC; j += 4) {
            float4 vt = *(const float4*)(pt + j); st += vt.x + vt.y + vt.z + vt.w;
            float4 vi = *(const float4*)(pi + j); si += vi.x + vi.y + vi.z + vi.w;
        }
        float cm = 0.5f * (st + si);
        float yp = fminf(fmaxf(cm, 1e-7f), 1.0f);
        float y1 = fminf(fmaxf(si, 1e-7f), 1.0f);
        float y2 = fminf(fmaxf(st, 1e-7f), 1.0f);
        float term = 0.5f * (y1 * logf(y1 / yp) + y2 * logf(y2 / yp));
        term = waveReduceSum(term);
        if (lane == 0) Cv[gw] = term;
    }
}

// ---------------------------------------------------------------- attn3: P lives in VGPRs.
// Phase 1: D[j,s] = Mth[j,:]·E[s,:] per 32-j chunk (M staged in LDS); lane holds P[j=4ch+r, s=l16]
//          which IS the scores A-frag under the permuted k-map slot(ch,j') -> 16*(j'>>2)+4*ch+(j'&3).
// Phase 2: barrier-free t-sweep; E B-frags loaded direct from L2 as two 8B halves matching the map.
// Max-free softmax (scores ~ N(0,1)); sums accumulated in LDS, flushed via global atomics.
__global__ __launch_bounds__(256, 3) void k_attn3(const f16* __restrict__ Eft, const f16* __restrict__ Efi,
                                                  const f16* __restrict__ Mth,
                                                  const float* __restrict__ Bst, const float* __restrict__ Bsi,
                                                  float* __restrict__ PEt, float* __restrict__ PBt,
                                                  float* __restrict__ PEi, float* __restrict__ PBi) {
    int x = blockIdx.x;
    const f16* E; const float* Bvg; float *PE, *PB;
    if (x < 512) { E = Eft; Bvg = Bst; PE = PEt; PB = PBt; }
    else         { x -= 512; E = Efi; Bvg = Bsi; PE = PEi; PB = PBi; }
    int b = x >> 5, h = (x >> 2) & 7;
    int s0 = (x & 3) * 128;
    const f16* Ebase = E + (size_t)b * NS * ND;
    const f16* Mh = Mth + (size_t)h * ND * ND;
    float* PEo = PE + (size_t)(b * NH + h) * NS;
    float* PBo = PB + (size_t)(b * NH + h) * NS;

    __shared__ f16 Ms[32 * 264];
    __shared__ float pe_s[NS], pb_s[NS];

    int tid = threadIdx.x;
    int lane = tid & 63, w = tid >> 6;
    int l16 = lane & 15, ch = lane >> 4;

    pe_s[tid] = 0.f; pe_s[tid + 256] = 0.f;
    pb_s[tid] = 0.f; pb_s[tid + 256] = 0.f;

    int sw0 = s0 + w * 32;   // this wave's 32 s-rows

    // hoist E B-frags for the P-phase (standard layout): 16 x 16B = 64 VGPRs
    f16x8 ebf[2][8];
    #pragma unroll
    for (int st = 0; st < 2; ++st)
        #pragma unroll
        for (int ki = 0; ki < 8; ++ki)
            ebf[st][ki] = *(const f16x8*)&Ebase[(size_t)(sw0 + st * 16 + l16) * ND + ki * 32 + ch * 8];

    // B-weights for this lane's 8 accumulator s-rows (s = sw0 + st*16 + 4*ch + r)
    float bvr[2][4];
    #pragma unroll
    for (int st = 0; st < 2; ++st)
        #pragma unroll
        for (int r = 0; r < 4; ++r)
            bvr[st][r] = Bvg[b * NS + sw0 + st * 16 + 4 * ch + r];

    // ---- phase 1: P into af[st][jc] (A-frag form, permuted k-map)
    f16x8 af[2][8];
    for (int jc = 0; jc < 8; ++jc) {
        __syncthreads();
        #pragma unroll
        for (int it = 0; it < 4; ++it) {
            int sid = tid + it * 256;
            int row = sid >> 5, seg = sid & 31;    // 32 rows x 32 segs of 16B
            *(int4*)&Ms[row * 264 + seg * 8] = *(const int4*)&Mh[(size_t)(jc * 32 + row) * ND + seg * 8];
        }
        __syncthreads();
        f32x4 acc[2][2] = {};   // [jTile(m)][sTile(n)]
        #pragma unroll
        for (int ki = 0; ki < 8; ++ki) {
            f16x8 a0 = *(const f16x8*)&Ms[(l16)      * 264 + ki * 32 + ch * 8];
            f16x8 a1 = *(const f16x8*)&Ms[(16 + l16) * 264 + ki * 32 + ch * 8];
            acc[0][0] = mfma16(a0, ebf[0][ki], acc[0][0]);
            acc[0][1] = mfma16(a0, ebf[1][ki], acc[0][1]);
            acc[1][0] = mfma16(a1, ebf[0][ki], acc[1][0]);
            acc[1][1] = mfma16(a1, ebf[1][ki], acc[1][1]);
        }
        #pragma unroll
        for (int st = 0; st < 2; ++st) {
            f16x8 v;
            #pragma unroll
            for (int r = 0; r < 4; ++r) { v[r] = (f16)acc[0][st][r]; v[4 + r] = (f16)acc[1][st][r]; }
            af[st][jc] = v;
        }
    }

    // ---- phase 2: barrier-free t-sweep
    for (int t0 = 0; t0 < NS; t0 += 64) {
        f32x4 sacc[2][4] = {};   // [sTile(m)][tTile(n)]
        #pragma unroll
        for (int kk = 0; kk < 8; ++kk)
            #pragma unroll
            for (int nt = 0; nt < 4; ++nt) {
                const f16* ep = &Ebase[(size_t)(t0 + nt * 16 + l16) * ND + kk * 32 + 4 * ch];
                f16x4 lo = *(const f16x4*)ep;
                f16x4 hi = *(const f16x4*)(ep + 16);
                f16x8 bf = { lo[0], lo[1], lo[2], lo[3], hi[0], hi[1], hi[2], hi[3] };
                sacc[0][nt] = mfma16(af[0][kk], bf, sacc[0][nt]);
                sacc[1][nt] = mfma16(af[1][kk], bf, sacc[1][nt]);
            }
        #pragma unroll
        for (int nt = 0; nt < 4; ++nt) {
            float se = 0.f, sw = 0.f;
            #pragma unroll
            for (int st = 0; st < 2; ++st)
                #pragma unroll
                for (int r = 0; r < 4; ++r) {
                    float e = __expf(sacc[st][nt][r] * 0.0625f);
                    se += e; sw += bvr[st][r] * e;
                }
            se += __shfl_down(se, 32); se += __shfl_down(se, 16);
            sw += __shfl_down(sw, 32); sw += __shfl_down(sw, 16);
            if (ch == 0) {
                atomicAdd(&pe_s[t0 + nt * 16 + l16], se);
                atomicAdd(&pb_s[t0 + nt * 16 + l16], sw);
            }
        }
    }
    __syncthreads();
    atomicAdd(&PEo[tid],       pe_s[tid]);
    atomicAdd(&PEo[tid + 256], pe_s[tid + 256]);
    atomicAdd(&PBo[tid],       pb_s[tid]);
    atomicAdd(&PBo[tid + 256], pb_s[tid + 256]);
}

// ---------------------------------------------------------------- cos + 2x layernorm + combine
__device__ inline float blockSum512(float v, float* rbuf) {
    v = waveReduceSum(v);
    int lane = threadIdx.x & 63, w = threadIdx.x >> 6;
    __syncthreads();
    if (lane == 0) rbuf[w] = v;
    __syncthreads();
    float s = 0.f;
    #pragma unroll
    for (int i = 0; i < 8; ++i) s += rbuf[i];
    return s;
}

__global__ __launch_bounds__(512) void k_final(const float* __restrict__ PEt, const float* __restrict__ PBt,
                                               const float* __restrict__ PEi, const float* __restrict__ PBi,
                                               const float* __restrict__ Cv,
                                               const float* __restrict__ gbs, const float* __restrict__ bbs,
                                               const float* __restrict__ gcs, const float* __restrict__ bcs,
                                               float* __restrict__ out) {
    __shared__ float rbuf[8];
    int b = blockIdx.x, s = threadIdx.x;
    float dot = 0.f, nt = 0.f, nu = 0.f;
    #pragma unroll
    for (int h = 0; h < NH; ++h) {
        size_t idx = (size_t)(b * NH + h) * NS + s;
        float tv = PBt[idx] / PEt[idx];
        float iv = PBi[idx] / PEi[idx];
        dot += tv * iv; nt += tv * tv; nu += iv * iv;
    }
    float cosv = -(dot * rsqrtf(fmaxf(nt, 1e-12f)) * rsqrtf(fmaxf(nu, 1e-12f)));

    float mc = blockSum512(cosv, rbuf) * (1.f / 512.f);
    float dc = cosv - mc;
    float vc = blockSum512(dc * dc, rbuf) * (1.f / 512.f);
    float BS = dc * rsqrtf(vc + 1e-16f) * gbs[s] + bbs[s];

    float cv = Cv[(size_t)b * NS + s];
    float mv = blockSum512(cv, rbuf) * (1.f / 512.f);
    float dv = cv - mv;
    float vv = blockSum512(dv * dv, rbuf) * (1.f / 512.f);
    float CS = dv * rsqrtf(vv + 1e-16f) * gcs[s] + bcs[s];

    out[(size_t)b * NS + s] = BS + CS;
    out[(size_t)NB * NS + (size_t)b * NS + s] = BS;
    out[(size_t)2 * NB * NS + (size_t)b * NS + s] = CS;
}

extern "C" void kernel_launch(void* const* d_in, const int* in_sizes, int n_in,
                              void* d_out, int out_size, void* d_ws, size_t ws_size,
                              hipStream_t stream) {
    const float* B_target   = (const float*)d_in[0];
    const float* B_infected = (const float*)d_in[1];
    const float* E_target   = (const float*)d_in[2];
    const float* E_infected = (const float*)d_in[3];
    const float* C_target   = (const float*)d_in[4];
    const float* C_infected = (const float*)d_in[5];
    const float* W1  = (const float*)d_in[8];
    const float* W2  = (const float*)d_in[9];
    const float* gbs = (const float*)d_in[10];
    const float* bbs = (const float*)d_in[11];
    const float* gcs = (const float*)d_in[12];
    const float* bcs = (const float*)d_in[13];
    float* out = (float*)d_out;

    char* ws = (char*)d_ws;
    size_t off = 0;
    auto alloc = [&](size_t n) { char* p = ws + off; off = (off + n + 255) & ~(size_t)255; return p; };
    float* Bt  = (float*)alloc((size_t)NB * NS * 4);
    float* Bi  = (float*)alloc((size_t)NB * NS * 4);
    float* Cv  = (float*)alloc((size_t)NB * NS * 4);
    float* PEt = (float*)alloc((size_t)NB * NH * NS * 4);   // contiguous 4-array group, one memset
    float* PBt = (float*)alloc((size_t)NB * NH * NS * 4);
    float* PEi = (float*)alloc((size_t)NB * NH * NS * 4);
    float* PBi = (float*)alloc((size_t)NB * NH * NS * 4);
    f16* Mth = (f16*)alloc((size_t)NH * ND * ND * 2);
    f16* Eft = (f16*)alloc((size_t)NB * NS * ND * 2);
    f16* Efi = (f16*)alloc((size_t)NB * NS * ND * 2);

    hipMemsetAsync(PEt, 0, (size_t)4 * NB * NH * NS * 4, stream);
    k_prep<<<128 + 8192 + 2048, 256, 0, stream>>>(W1, W2, Mth,
                                                  E_target, E_infected, Eft, Efi,
                                                  B_target, B_infected, Bt, Bi,
                                                  C_target, C_infected, Cv);
    k_attn3<<<1024, 256, 0, stream>>>(Eft, Efi, Mth, Bt, Bi, PEt, PBt, PEi, PBi);
    k_final<<<NB, 512, 0, stream>>>(PEt, PBt, PEi, PBi, Cv, gbs, bbs, gcs, bcs, out);
}

// Round 6
// 316.780 us; speedup vs baseline: 1.5742x; 1.5742x over previous
//
#include <hip/hip_runtime.h>

#define NB 16
#define NS 512
#define ND 256
#define NH 8
#define NFB 128
#define NK 64
#define NFC 32

using f16 = _Float16;
using f16x4 = __attribute__((ext_vector_type(4))) f16;
using f16x8 = __attribute__((ext_vector_type(8))) f16;
using f32x4 = __attribute__((ext_vector_type(4))) float;

__device__ inline float waveReduceSum(float v) {
    #pragma unroll
    for (int off = 32; off; off >>= 1) v += __shfl_down(v, off);
    return v;
}

__device__ inline f32x4 mfma16(f16x8 a, f16x8 b, f32x4 c) {
    return __builtin_amdgcn_mfma_f32_16x16x32_f16(a, b, c, 0, 0, 0);
}

// ---------------------------------------------------------------- prep: mt | convert | bsum | cv in one dispatch
__global__ __launch_bounds__(256) void k_prep(const float* __restrict__ W1, const float* __restrict__ W2,
                                              f16* __restrict__ Mth,
                                              const float* __restrict__ Et_in, const float* __restrict__ Ei_in,
                                              f16* __restrict__ Ot, f16* __restrict__ Oi,
                                              const float* __restrict__ Bt_in, const float* __restrict__ Bi_in,
                                              float* __restrict__ Bt, float* __restrict__ Bi,
                                              const float* __restrict__ Ct, const float* __restrict__ Ci,
                                              float* __restrict__ Cv) {
    __shared__ float Wa[64][36];
    __shared__ float Wb[64][36];
    int bid = blockIdx.x;
    int tid = threadIdx.x;

    if (bid < 128) {
        // ---- Mt[h][j][i] = sum_e W2[h,j,e]*W1[h,i,e]
        int h  = bid >> 4;
        int j0 = ((bid >> 2) & 3) * 64;
        int i0 = (bid & 3) * 64;
        const float* A  = W2 + (size_t)h * ND * ND;
        const float* Bm = W1 + (size_t)h * ND * ND;
        int r = tid >> 4, c = tid & 15;
        float acc[4][4] = {};
        for (int d0 = 0; d0 < ND; d0 += 32) {
            __syncthreads();
            #pragma unroll
            for (int i = 0; i < 2; ++i) {
                int sid = tid + i * 256;
                int row = sid >> 3, seg = sid & 7;
                *(float4*)&Wa[row][seg * 4] = *(const float4*)&A [(size_t)(j0 + row) * ND + d0 + seg * 4];
                *(float4*)&Wb[row][seg * 4] = *(const float4*)&Bm[(size_t)(i0 + row) * ND + d0 + seg * 4];
            }
            __syncthreads();
            #pragma unroll 8
            for (int d = 0; d < 32; ++d) {
                float a0 = Wa[r*4+0][d], a1 = Wa[r*4+1][d], a2 = Wa[r*4+2][d], a3 = Wa[r*4+3][d];
                float b0 = Wb[c*4+0][d], b1 = Wb[c*4+1][d], b2 = Wb[c*4+2][d], b3 = Wb[c*4+3][d];
                acc[0][0] += a0*b0; acc[0][1] += a0*b1; acc[0][2] += a0*b2; acc[0][3] += a0*b3;
                acc[1][0] += a1*b0; acc[1][1] += a1*b1; acc[1][2] += a1*b2; acc[1][3] += a1*b3;
                acc[2][0] += a2*b0; acc[2][1] += a2*b1; acc[2][2] += a2*b2; acc[2][3] += a2*b3;
                acc[3][0] += a3*b0; acc[3][1] += a3*b1; acc[3][2] += a3*b2; acc[3][3] += a3*b3;
            }
        }
        #pragma unroll
        for (int a = 0; a < 4; ++a)
            #pragma unroll
            for (int bb = 0; bb < 4; ++bb)
                Mth[(size_t)h * ND * ND + (size_t)(j0 + r * 4 + a) * ND + (i0 + c * 4 + bb)] = (f16)acc[a][bb];
    } else if (bid < 128 + 4096) {
        // ---- convert E -> f16
        const int n4 = NB * NS * ND / 4;
        int i = (bid - 128) * 256 + tid;
        const float* src; f16* dst;
        if (i < n4) { src = Et_in; dst = Ot; }
        else        { src = Ei_in; dst = Oi; i -= n4; }
        float4 v = ((const float4*)src)[i];
        f16x4 o = { (f16)v.x, (f16)v.y, (f16)v.z, (f16)v.w };
        ((f16x4*)dst)[i] = o;
    } else if (bid < 128 + 8192) {
        // ---- Bvec = sum over FB
        int wid = ((bid - 128 - 4096) * 256 + tid) >> 6;
        int lane = tid & 63;
        const float* src; float* dst; int row;
        if (wid < NB * NS) { src = Bt_in; dst = Bt; row = wid; }
        else               { src = Bi_in; dst = Bi; row = wid - NB * NS; }
        float2 v = ((const float2*)(src + (size_t)row * NFB))[lane];
        float s = waveReduceSum(v.x + v.y);
        if (lane == 0) dst[row] = s;
    } else {
        // ---- Cv = 0.5*KLD(Ci,Cm)+0.5*KLD(Ct,Cm)
        int gw = ((bid - 128 - 8192) * 256 + tid) >> 6;
        int lane = tid & 63;
        const float* pt = Ct + ((size_t)gw * NK + lane) * NFC;
        const float* pi = Ci + ((size_t)gw * NK + lane) * NFC;
        float st = 0.f, si = 0.f;
        #pragma unroll
        for (int j = 0; j < NFC; j += 4) {
            float4 vt = *(const float4*)(pt + j); st += vt.x + vt.y + vt.z + vt.w;
            float4 vi = *(const float4*)(pi + j); si += vi.x + vi.y + vi.z + vi.w;
        }
        float cm = 0.5f * (st + si);
        float yp = fminf(fmaxf(cm, 1e-7f), 1.0f);
        float y1 = fminf(fmaxf(si, 1e-7f), 1.0f);
        float y2 = fminf(fmaxf(st, 1e-7f), 1.0f);
        float term = 0.5f * (y1 * logf(y1 / yp) + y2 * logf(y2 / yp));
        term = waveReduceSum(term);
        if (lane == 0) Cv[gw] = term;
    }
}

// ---------------------------------------------------------------- attn4: P in VGPRs (R5 phase-1, proven) +
// phase-2 t-sweep with DOUBLE-BUFFERED LDS Et tiles (coalesced int4 staging, register prefetch, 1 barrier/iter).
// B-frags from LDS as two ds_read_b64 at the permuted k-map offsets (4ch, 16+4ch) — same math as R5 (validated).
// Max-free softmax (scores ~ N(0,1)); sums in LDS, flushed via global atomics.
__global__ __launch_bounds__(256, 2) void k_attn4(const f16* __restrict__ Eft, const f16* __restrict__ Efi,
                                                  const f16* __restrict__ Mth,
                                                  const float* __restrict__ Bst, const float* __restrict__ Bsi,
                                                  float* __restrict__ PEt, float* __restrict__ PBt,
                                                  float* __restrict__ PEi, float* __restrict__ PBi) {
    int x = blockIdx.x;
    const f16* E; const float* Bvg; float *PE, *PB;
    if (x < 512) { E = Eft; Bvg = Bst; PE = PEt; PB = PBt; }
    else         { x -= 512; E = Efi; Bvg = Bsi; PE = PEi; PB = PBi; }
    int b = x >> 5, h = (x >> 2) & 7;
    int s0 = (x & 3) * 128;
    const f16* Ebase = E + (size_t)b * NS * ND;
    const f16* Mh = Mth + (size_t)h * ND * ND;
    float* PEo = PE + (size_t)(b * NH + h) * NS;
    float* PBo = PB + (size_t)(b * NH + h) * NS;

    __shared__ f16 smem[2 * 64 * 264];      // phase1: Ms aliases smem[0..32*264); phase2: two Et buffers
    __shared__ float pe_s[NS], pb_s[NS];

    int tid = threadIdx.x;
    int lane = tid & 63, w = tid >> 6;
    int l16 = lane & 15, ch = lane >> 4;

    pe_s[tid] = 0.f; pe_s[tid + 256] = 0.f;
    pb_s[tid] = 0.f; pb_s[tid + 256] = 0.f;

    int sw0 = s0 + w * 32;   // this wave's 32 s-rows

    // hoist E B-frags for the P-phase (standard layout): 16 x 16B = 64 VGPRs
    f16x8 ebf[2][8];
    #pragma unroll
    for (int st = 0; st < 2; ++st)
        #pragma unroll
        for (int ki = 0; ki < 8; ++ki)
            ebf[st][ki] = *(const f16x8*)&Ebase[(size_t)(sw0 + st * 16 + l16) * ND + ki * 32 + ch * 8];

    // B-weights for this lane's 8 accumulator s-rows (s = sw0 + st*16 + 4*ch + r)
    float bvr[2][4];
    #pragma unroll
    for (int st = 0; st < 2; ++st)
        #pragma unroll
        for (int r = 0; r < 4; ++r)
            bvr[st][r] = Bvg[b * NS + sw0 + st * 16 + 4 * ch + r];

    // ---- phase 1: P into af[st][jc] (A-frag form, permuted k-map slot(ch,j') -> 16*(j'>>2)+4*ch+(j'&3))
    f16x8 af[2][8];
    for (int jc = 0; jc < 8; ++jc) {
        __syncthreads();
        #pragma unroll
        for (int it = 0; it < 4; ++it) {
            int sid = tid + it * 256;
            int row = sid >> 5, seg = sid & 31;    // 32 rows x 32 segs of 16B
            *(int4*)&smem[row * 264 + seg * 8] = *(const int4*)&Mh[(size_t)(jc * 32 + row) * ND + seg * 8];
        }
        __syncthreads();
        f32x4 acc[2][2] = {};   // [jTile(m)][sTile(n)]
        #pragma unroll
        for (int ki = 0; ki < 8; ++ki) {
            f16x8 a0 = *(const f16x8*)&smem[(l16)      * 264 + ki * 32 + ch * 8];
            f16x8 a1 = *(const f16x8*)&smem[(16 + l16) * 264 + ki * 32 + ch * 8];
            acc[0][0] = mfma16(a0, ebf[0][ki], acc[0][0]);
            acc[0][1] = mfma16(a0, ebf[1][ki], acc[0][1]);
            acc[1][0] = mfma16(a1, ebf[0][ki], acc[1][0]);
            acc[1][1] = mfma16(a1, ebf[1][ki], acc[1][1]);
        }
        #pragma unroll
        for (int st = 0; st < 2; ++st) {
            f16x8 v;
            #pragma unroll
            for (int r = 0; r < 4; ++r) { v[r] = (f16)acc[0][st][r]; v[4 + r] = (f16)acc[1][st][r]; }
            af[st][jc] = v;
        }
    }
    __syncthreads();   // last Ms reads done before buffer 0 is overwritten

    // ---- phase 2: double-buffered t-sweep, 64-row tiles, 1 barrier/iter
    int4 v[8];
    #pragma unroll
    for (int i = 0; i < 8; ++i) {
        int sid = tid + i * 256;
        int row = sid >> 5, seg = sid & 31;
        v[i] = *(const int4*)&Ebase[(size_t)row * ND + seg * 8];
    }
    #pragma unroll
    for (int i = 0; i < 8; ++i) {
        int sid = tid + i * 256;
        int row = sid >> 5, seg = sid & 31;
        *(int4*)&smem[row * 264 + seg * 8] = v[i];
    }

    for (int t = 0; t < 8; ++t) {
        f16* cur = smem + (t & 1) * (64 * 264);
        f16* nxt = smem + ((t + 1) & 1) * (64 * 264);
        if (t < 7) {
            int t0n = (t + 1) * 64;
            #pragma unroll
            for (int i = 0; i < 8; ++i) {
                int sid = tid + i * 256;
                int row = sid >> 5, seg = sid & 31;
                v[i] = *(const int4*)&Ebase[(size_t)(t0n + row) * ND + seg * 8];
            }
        }
        __syncthreads();   // cur writes visible; nxt reads (iter t-1) done
        int t0 = t * 64;
        f32x4 sacc[2][4] = {};   // [sTile(m)][tTile(n)]
        #pragma unroll
        for (int kk = 0; kk < 8; ++kk)
            #pragma unroll
            for (int nt = 0; nt < 4; ++nt) {
                const f16* ep = &cur[(nt * 16 + l16) * 264 + kk * 32 + 4 * ch];
                f16x4 lo = *(const f16x4*)ep;
                f16x4 hi = *(const f16x4*)(ep + 16);
                f16x8 bf = { lo[0], lo[1], lo[2], lo[3], hi[0], hi[1], hi[2], hi[3] };
                sacc[0][nt] = mfma16(af[0][kk], bf, sacc[0][nt]);
                sacc[1][nt] = mfma16(af[1][kk], bf, sacc[1][nt]);
            }
        if (t < 7) {
            #pragma unroll
            for (int i = 0; i < 8; ++i) {
                int sid = tid + i * 256;
                int row = sid >> 5, seg = sid & 31;
                *(int4*)&nxt[row * 264 + seg * 8] = v[i];
            }
        }
        #pragma unroll
        for (int nt = 0; nt < 4; ++nt) {
            float se = 0.f, sw = 0.f;
            #pragma unroll
            for (int st = 0; st < 2; ++st)
                #pragma unroll
                for (int r = 0; r < 4; ++r) {
                    float e = __expf(sacc[st][nt][r] * 0.0625f);
                    se += e; sw += bvr[st][r] * e;
                }
            se += __shfl_down(se, 32); se += __shfl_down(se, 16);
            sw += __shfl_down(sw, 32); sw += __shfl_down(sw, 16);
            if (ch == 0) {
                atomicAdd(&pe_s[t0 + nt * 16 + l16], se);
                atomicAdd(&pb_s[t0 + nt * 16 + l16], sw);
            }
        }
    }
    __syncthreads();
    atomicAdd(&PEo[tid],       pe_s[tid]);
    atomicAdd(&PEo[tid + 256], pe_s[tid + 256]);
    atomicAdd(&PBo[tid],       pb_s[tid]);
    atomicAdd(&PBo[tid + 256], pb_s[tid + 256]);
}

// ---------------------------------------------------------------- cos + 2x layernorm + combine
__device__ inline float blockSum512(float v, float* rbuf) {
    v = waveReduceSum(v);
    int lane = threadIdx.x & 63, w = threadIdx.x >> 6;
    __syncthreads();
    if (lane == 0) rbuf[w] = v;
    __syncthreads();
    float s = 0.f;
    #pragma unroll
    for (int i = 0; i < 8; ++i) s += rbuf[i];
    return s;
}

__global__ __launch_bounds__(512) void k_final(const float* __restrict__ PEt, const float* __restrict__ PBt,
                                               const float* __restrict__ PEi, const float* __restrict__ PBi,
                                               const float* __restrict__ Cv,
                                               const float* __restrict__ gbs, const float* __restrict__ bbs,
                                               const float* __restrict__ gcs, const float* __restrict__ bcs,
                                               float* __restrict__ out) {
    __shared__ float rbuf[8];
    int b = blockIdx.x, s = threadIdx.x;
    float dot = 0.f, nt = 0.f, nu = 0.f;
    #pragma unroll
    for (int h = 0; h < NH; ++h) {
        size_t idx = (size_t)(b * NH + h) * NS + s;
        float tv = PBt[idx] / PEt[idx];
        float iv = PBi[idx] / PEi[idx];
        dot += tv * iv; nt += tv * tv; nu += iv * iv;
    }
    float cosv = -(dot * rsqrtf(fmaxf(nt, 1e-12f)) * rsqrtf(fmaxf(nu, 1e-12f)));

    float mc = blockSum512(cosv, rbuf) * (1.f / 512.f);
    float dc = cosv - mc;
    float vc = blockSum512(dc * dc, rbuf) * (1.f / 512.f);
    float BS = dc * rsqrtf(vc + 1e-16f) * gbs[s] + bbs[s];

    float cv = Cv[(size_t)b * NS + s];
    float mv = blockSum512(cv, rbuf) * (1.f / 512.f);
    float dv = cv - mv;
    float vv = blockSum512(dv * dv, rbuf) * (1.f / 512.f);
    float CS = dv * rsqrtf(vv + 1e-16f) * gcs[s] + bcs[s];

    out[(size_t)b * NS + s] = BS + CS;
    out[(size_t)NB * NS + (size_t)b * NS + s] = BS;
    out[(size_t)2 * NB * NS + (size_t)b * NS + s] = CS;
}

extern "C" void kernel_launch(void* const* d_in, const int* in_sizes, int n_in,
                              void* d_out, int out_size, void* d_ws, size_t ws_size,
                              hipStream_t stream) {
    const float* B_target   = (const float*)d_in[0];
    const float* B_infected = (const float*)d_in[1];
    const float* E_target   = (const float*)d_in[2];
    const float* E_infected = (const float*)d_in[3];
    const float* C_target   = (const float*)d_in[4];
    const float* C_infected = (const float*)d_in[5];
    const float* W1  = (const float*)d_in[8];
    const float* W2  = (const float*)d_in[9];
    const float* gbs = (const float*)d_in[10];
    const float* bbs = (const float*)d_in[11];
    const float* gcs = (const float*)d_in[12];
    const float* bcs = (const float*)d_in[13];
    float* out = (float*)d_out;

    char* ws = (char*)d_ws;
    size_t off = 0;
    auto alloc = [&](size_t n) { char* p = ws + off; off = (off + n + 255) & ~(size_t)255; return p; };
    float* Bt  = (float*)alloc((size_t)NB * NS * 4);
    float* Bi  = (float*)alloc((size_t)NB * NS * 4);
    float* Cv  = (float*)alloc((size_t)NB * NS * 4);
    float* PEt = (float*)alloc((size_t)NB * NH * NS * 4);   // contiguous 4-array group, one memset
    float* PBt = (float*)alloc((size_t)NB * NH * NS * 4);
    float* PEi = (float*)alloc((size_t)NB * NH * NS * 4);
    float* PBi = (float*)alloc((size_t)NB * NH * NS * 4);
    f16* Mth = (f16*)alloc((size_t)NH * ND * ND * 2);
    f16* Eft = (f16*)alloc((size_t)NB * NS * ND * 2);
    f16* Efi = (f16*)alloc((size_t)NB * NS * ND * 2);

    hipMemsetAsync(PEt, 0, (size_t)4 * NB * NH * NS * 4, stream);
    k_prep<<<128 + 8192 + 2048, 256, 0, stream>>>(W1, W2, Mth,
                                                  E_target, E_infected, Eft, Efi,
                                                  B_target, B_infected, Bt, Bi,
                                                  C_target, C_infected, Cv);
    k_attn4<<<1024, 256, 0, stream>>>(Eft, Efi, Mth, Bt, Bi, PEt, PBt, PEi, PBi);
    k_final<<<NB, 512, 0, stream>>>(PEt, PBt, PEi, PBi, Cv, gbs, bbs, gcs, bcs, out);
}